// Round 1
// baseline (58.919 us; speedup 1.0000x reference)
//
#include <hip/hip_runtime.h>
#include <hip/hip_bf16.h>

// Closed-form solution of the circuit:
//   state before CNOTs is the product state  ⊗_w  RY(p[w]+p[w+20]) RX(x[b,w]) |0>
//   (RY layer: param i hits wire i%20; same-wire RYs add angles; distinct-wire
//    1q gates commute).
//   CNOT chain in Heisenberg picture: C† Z_w C = Z_0 Z_1 ... Z_w.
//   On the product state, <Z_k> = cos(x[b,k]) * cos(p[k]+p[k+20]).
//   => out[b,w] = prefix product over k<=w of cos(x[b,k])*cos(p[k]+p[k+20]).

#define N_WIRES 20
#define BATCH 32

__global__ __launch_bounds__(64)
void quantum_closed_form_kernel(const float* __restrict__ x,
                                const float* __restrict__ params,
                                float* __restrict__ out) {
    __shared__ double cosp[N_WIRES];
    const int t = threadIdx.x;

    // cos(params[w] + params[w+20]) for each wire, in double for safety.
    if (t < N_WIRES) {
        cosp[t] = cos((double)params[t] + (double)params[t + N_WIRES]);
    }
    __syncthreads();

    if (t < BATCH) {
        double prod = 1.0;
        const float* xr = x + t * N_WIRES;
        float* orow = out + t * N_WIRES;
#pragma unroll
        for (int w = 0; w < N_WIRES; ++w) {
            prod *= cos((double)xr[w]) * cosp[w];
            orow[w] = (float)prod;
        }
    }
}

extern "C" void kernel_launch(void* const* d_in, const int* in_sizes, int n_in,
                              void* d_out, int out_size, void* d_ws, size_t ws_size,
                              hipStream_t stream) {
    const float* x = (const float*)d_in[0];       // (32, 20) float32
    const float* params = (const float*)d_in[1];  // (40,)   float32
    float* out = (float*)d_out;                   // (32, 20) float32

    quantum_closed_form_kernel<<<1, 64, 0, stream>>>(x, params, out);
}